// Round 5
// baseline (601.486 us; speedup 1.0000x reference)
//
#include <hip/hip_runtime.h>

#define HW_ 65536
#define W_ 1024
#define H_ 64
#define C_ 68
#define NPIX 131072
#define EPS 1e-5f

// ws float layout:
//   P1 [34][1024] @ 0       stats1 partials (0-7 ta, 8-15 ta^2, 16-23 tg, 24-31 tg^2, 32 nmsel, 33 ncenter)
//   P2 [16][1024] @ 34816   stats2 partials
//   AT [128][1024] @ 51200  abn partials (0-63 sum, 64-127 sumsq)
//   FIN @ 182272            FIN1[34], FIN2[16] @+34, FINA[128] @+50
//   CNT @ 182464            3 uint ticket counters (memset 0 each launch)
//   out_pre bf16 @ byte 730112, NPIX*64 elements
#define P1OFF 0
#define P2OFF 34816
#define ATOFF 51200
#define FINOFF 182272
#define CNTBYTE 729856
#define OUTPRE_BYTE 730112

typedef __attribute__((ext_vector_type(8))) short short8;
typedef __attribute__((ext_vector_type(4))) float floatx4;

__device__ __forceinline__ unsigned short f2bf(float f) {
  unsigned u = __float_as_uint(f);
  u += 0x7fffu + ((u >> 16) & 1u);
  return (unsigned short)(u >> 16);
}
__device__ __forceinline__ unsigned pack2(float a, float b) {
  return (unsigned)f2bf(a) | ((unsigned)f2bf(b) << 16);
}
__device__ __forceinline__ float bf2f(unsigned short u) {
  return __uint_as_float(((unsigned)u) << 16);
}
__device__ __forceinline__ float wred(float v) {
  v += __shfl_xor(v, 1);  v += __shfl_xor(v, 2);  v += __shfl_xor(v, 4);
  v += __shfl_xor(v, 8);  v += __shfl_xor(v, 16); v += __shfl_xor(v, 32);
  return v;
}

// ---------------- K1: stats1 (k-split, 2 th/px) + last-block reduce ----------
__global__ __launch_bounds__(256, 4) void k_stats1(
    const float* __restrict__ x, const float* __restrict__ mask,
    const float* __restrict__ w1, const float* __restrict__ g1,
    float* __restrict__ ws) {
  __shared__ float red[136];
  __shared__ int islast;
  const int tid = threadIdx.x, bid = blockIdx.x;
  const int lane = tid & 63, wave = tid >> 6;

  const int tile = (bid & 7) * 128 + (bid >> 3);
  const int b = tile >> 9;
  const int s0 = (tile & 511) * 128;
  const int px = tid & 127;
  const int half = tid >> 7;
  const int s = s0 + px;
  const int h = s >> 10, w = s & (W_ - 1);
  const float* xb = x + (size_t)b * C_ * HW_;
  const float* mb = mask + (size_t)b * HW_;
  const int kbase = half ? 4 : 0;
  const int kcnt = half ? 5 : 4;

  float acc[34];
#pragma unroll
  for (int i = 0; i < 34; i++) acc[i] = 0.f;
  float xc0 = xb[s], xc1 = xb[HW_ + s], xc2 = xb[2 * HW_ + s], xc3 = xb[3 * HW_ + s];
  if (half == 0) acc[33] = (mb[s] > 0.f) ? 1.f : 0.f;
#pragma unroll
  for (int kk = 0; kk < 5; kk++) {
    if (kk < kcnt) {
      int k = kbase + kk;
      int di = k / 3 - 1, dj = k % 3 - 1;
      int hh = h + di, ww = w + dj;
      bool inb = ((unsigned)hh < (unsigned)H_) && ((unsigned)ww < (unsigned)W_);
      int ns = inb ? hh * W_ + ww : s;
      float mk = (inb && mb[ns] > 0.f) ? 1.f : 0.f;
      float pn0 = xb[ns] - xc0;
      float pn1 = xb[HW_ + ns] - xc1;
      float pn2 = xb[2 * HW_ + ns] - xc2;
      float pn3 = xb[3 * HW_ + ns] - xc3;
      acc[32] += mk;
#pragma unroll
      for (int o = 0; o < 8; o++) {
        float ta = pn0 * w1[o * 4] + pn1 * w1[o * 4 + 1] + pn2 * w1[o * 4 + 2] + pn3 * w1[o * 4 + 3];
        acc[o] += mk * ta; acc[8 + o] += mk * ta * ta;
        float tg = pn0 * g1[o * 4] + pn1 * g1[o * 4 + 1] + pn2 * g1[o * 4 + 2] + pn3 * g1[o * 4 + 3];
        acc[16 + o] += mk * tg; acc[24 + o] += mk * tg * tg;
      }
    }
  }
#pragma unroll
  for (int i = 0; i < 34; i++) {
    float r = wred(acc[i]);
    if (lane == 0) red[wave * 34 + i] = r;
  }
  __syncthreads();
  if (tid < 34)
    ws[P1OFF + tid * 1024 + bid] = red[tid] + red[34 + tid] + red[68 + tid] + red[102 + tid];
  __threadfence();
  __syncthreads();
  if (tid == 0) {
    unsigned* cnt = (unsigned*)((char*)ws + CNTBYTE);
    islast = (atomicAdd(cnt, 1u) == 1023u);
  }
  __syncthreads();
  if (islast) {
    __threadfence();
    for (int i = wave; i < 34; i += 4) {
      const float* src = ws + P1OFF + i * 1024;
      float v = 0.f;
#pragma unroll
      for (int j = 0; j < 16; j++) v += src[lane + j * 64];
      v = wred(v);
      if (lane == 0) ws[FINOFF + i] = v;
    }
  }
}

// ---------------- K2: stats2 (k-split) + last-block reduce ------------------
__global__ __launch_bounds__(256, 4) void k_stats2(
    const float* __restrict__ x, const float* __restrict__ mask,
    const float* __restrict__ g1, const float* __restrict__ gbn1_g,
    const float* __restrict__ gbn1_b, const float* __restrict__ g2,
    float* __restrict__ ws) {
  __shared__ float scl[16];
  __shared__ float red[64];
  __shared__ int islast;
  const int tid = threadIdx.x, bid = blockIdx.x;
  const int lane = tid & 63, wave = tid >> 6;

  if (tid < 8) {
    float n = fmaxf(ws[FINOFF + 32], 1.f);
    float mean = ws[FINOFF + 16 + tid] / n;
    float var = ws[FINOFF + 24 + tid] / n - mean * mean;
    float sv = gbn1_g[tid] * rsqrtf(var + EPS);
    scl[tid] = sv;
    scl[8 + tid] = gbn1_b[tid] - mean * sv;
  }
  __syncthreads();

  const int tile = (bid & 7) * 128 + (bid >> 3);
  const int b = tile >> 9;
  const int s0 = (tile & 511) * 128;
  const int px = tid & 127;
  const int half = tid >> 7;
  const int s = s0 + px;
  const int h = s >> 10, w = s & (W_ - 1);
  const float* xb = x + (size_t)b * C_ * HW_;
  const float* mb = mask + (size_t)b * HW_;
  const int kbase = half ? 4 : 0;
  const int kcnt = half ? 5 : 4;

  float acc[16];
#pragma unroll
  for (int i = 0; i < 16; i++) acc[i] = 0.f;
  float xc0 = xb[s], xc1 = xb[HW_ + s], xc2 = xb[2 * HW_ + s], xc3 = xb[3 * HW_ + s];
#pragma unroll
  for (int kk = 0; kk < 5; kk++) {
    if (kk < kcnt) {
      int k = kbase + kk;
      int di = k / 3 - 1, dj = k % 3 - 1;
      int hh = h + di, ww = w + dj;
      bool inb = ((unsigned)hh < (unsigned)H_) && ((unsigned)ww < (unsigned)W_);
      int ns = inb ? hh * W_ + ww : s;
      float mk = (inb && mb[ns] > 0.f) ? 1.f : 0.f;
      float pn0 = xb[ns] - xc0;
      float pn1 = xb[HW_ + ns] - xc1;
      float pn2 = xb[2 * HW_ + ns] - xc2;
      float pn3 = xb[3 * HW_ + ns] - xc3;
      float gb[8];
#pragma unroll
      for (int o = 0; o < 8; o++) {
        float tg = pn0 * g1[o * 4] + pn1 * g1[o * 4 + 1] + pn2 * g1[o * 4 + 2] + pn3 * g1[o * 4 + 3];
        gb[o] = fmaxf(scl[o] * tg + scl[8 + o], 0.f);
      }
#pragma unroll
      for (int j = 0; j < 8; j++) {
        float t2 = 0.f;
#pragma unroll
        for (int o = 0; o < 8; o++) t2 += gb[o] * g2[j * 8 + o];
        acc[j] += mk * t2; acc[8 + j] += mk * t2 * t2;
      }
    }
  }
#pragma unroll
  for (int i = 0; i < 16; i++) {
    float r = wred(acc[i]);
    if (lane == 0) red[wave * 16 + i] = r;
  }
  __syncthreads();
  if (tid < 16)
    ws[P2OFF + tid * 1024 + bid] = red[tid] + red[16 + tid] + red[32 + tid] + red[48 + tid];
  __threadfence();
  __syncthreads();
  if (tid == 0) {
    unsigned* cnt = (unsigned*)((char*)ws + CNTBYTE);
    islast = (atomicAdd(cnt + 1, 1u) == 1023u);
  }
  __syncthreads();
  if (islast) {
    __threadfence();
    for (int i = wave; i < 16; i += 4) {
      const float* src = ws + P2OFF + i * 1024;
      float v = 0.f;
#pragma unroll
      for (int j = 0; j < 16; j++) v += src[lane + j * 64];
      v = wred(v);
      if (lane == 0) ws[FINOFF + 34 + i] = v;
    }
  }
}

// --------- K3: fused vec build (k-split softmax) + MFMA GEMM + abn partials -
__global__ __launch_bounds__(256, 4) void k_fused(
    const float* __restrict__ x, const float* __restrict__ mask,
    const float* __restrict__ w1, const float* __restrict__ bn1_g,
    const float* __restrict__ bn1_b, const float* __restrict__ w2,
    const float* __restrict__ b2, const float* __restrict__ g1,
    const float* __restrict__ g2, const float* __restrict__ gbn1_g,
    const float* __restrict__ gbn1_b, const float* __restrict__ gbn2_g,
    const float* __restrict__ gbn2_b, const float* __restrict__ w_agg,
    float* __restrict__ ws) {
  // LDS: vecT 34816 | scratch 4608 (wtL / rS+rQ) | scl 192
  __shared__ __align__(16) char smem[34816 + 4608 + 192];
  uint4(*vecT)[128] = (uint4(*)[128])smem;
  float* scratch = (float*)(smem + 34816);
  float* scl = (float*)(smem + 34816 + 4608);  // sA@0 hA@8 sG1@16 hG1@24 sG2@32 hG2@40
  float* exm = (float*)smem;                   // [2][128] aliases vecT[0..1] (dead before fagg)
  float* den2 = (float*)(smem + 1024);
  __shared__ int islast;

  const int tid = threadIdx.x, bid = blockIdx.x;
  const int lane = tid & 63, wave = tid >> 6;

  if (tid < 24) {
    int o = tid & 7;
    float n = fmaxf(ws[FINOFF + 32], 1.f);
    float sum, sum2, gma, bta;
    if (tid < 8)       { sum = ws[FINOFF + o];      sum2 = ws[FINOFF + 8 + o];  gma = bn1_g[o];  bta = bn1_b[o]; }
    else if (tid < 16) { sum = ws[FINOFF + 16 + o]; sum2 = ws[FINOFF + 24 + o]; gma = gbn1_g[o]; bta = gbn1_b[o]; }
    else               { sum = ws[FINOFF + 34 + o]; sum2 = ws[FINOFF + 42 + o]; gma = gbn2_g[o]; bta = gbn2_b[o]; }
    float mean = sum / n, var = sum2 / n - mean * mean;
    float sv = gma * rsqrtf(var + EPS);
    scl[(tid >> 3) * 16 + o] = sv;
    scl[(tid >> 3) * 16 + 8 + o] = bta - mean * sv;
  }
  __syncthreads();

  const int tile = (bid & 7) * 128 + (bid >> 3);
  const int b = tile >> 9;
  const int s0 = (tile & 511) * 128;
  const int px = tid & 127;
  const int half = tid >> 7;  // wave-uniform
  const int s = s0 + px;
  const int h = s >> 10, w = s & (W_ - 1);
  const float* xb = x + (size_t)b * C_ * HW_;
  const float* mb = mask + (size_t)b * HW_;
  const int kbase = half ? 4 : 0;
  const int kcnt = half ? 5 : 4;

  float xc0 = xb[s], xc1 = xb[HW_ + s], xc2 = xb[2 * HW_ + s], xc3 = xb[3 * HW_ + s];
  float b2v = b2[0];
  float evL[5], mkL[5]; int nsL[5];
  float mx = -1e30f;
#pragma unroll
  for (int kk = 0; kk < 5; kk++) {
    if (kk < kcnt) {
      int k = kbase + kk;
      int di = k / 3 - 1, dj = k % 3 - 1;
      int hh = h + di, ww = w + dj;
      bool inb = ((unsigned)hh < (unsigned)H_) && ((unsigned)ww < (unsigned)W_);
      int ns = inb ? hh * W_ + ww : s;
      nsL[kk] = ns;
      float mk = (inb && mb[ns] > 0.f) ? 1.f : 0.f;
      mkL[kk] = mk;
      float pn0 = xb[ns] - xc0;
      float pn1 = xb[HW_ + ns] - xc1;
      float pn2 = xb[2 * HW_ + ns] - xc2;
      float pn3 = xb[3 * HW_ + ns] - xc3;
      float accw = 0.f;
#pragma unroll
      for (int o = 0; o < 8; o++) {
        float ta = pn0 * w1[o * 4] + pn1 * w1[o * 4 + 1] + pn2 * w1[o * 4 + 2] + pn3 * w1[o * 4 + 3];
        accw += fmaxf(scl[o] * ta + scl[8 + o], 0.f) * w2[o];
      }
      float wp = mk * (accw + b2v);
      evL[kk] = wp;
      mx = fmaxf(mx, wp);
    }
  }
  exm[half * 128 + px] = mx;
  __syncthreads();
  float gmx = fmaxf(exm[px], exm[128 + px]);
  float dp = 0.f;
#pragma unroll
  for (int kk = 0; kk < 5; kk++)
    if (kk < kcnt) { evL[kk] = __expf(evL[kk] - gmx); dp += evL[kk]; }
  den2[half * 128 + px] = dp;
  __syncthreads();
  float inv = 1.f / (den2[px] + den2[128 + px]);

  // own k's: wt -> wtL(scratch), weighted g -> vecT[8+k]
#pragma unroll
  for (int kk = 0; kk < 5; kk++) {
    if (kk < kcnt) {
      int k = kbase + kk;
      float wt = evL[kk] * inv;
      scratch[k * 128 + px] = wt;
      int ns = nsL[kk];
      float wg = wt * mkL[kk];
      float pn0 = xb[ns] - xc0;
      float pn1 = xb[HW_ + ns] - xc1;
      float pn2 = xb[2 * HW_ + ns] - xc2;
      float pn3 = xb[3 * HW_ + ns] - xc3;
      float gb[8];
#pragma unroll
      for (int o = 0; o < 8; o++) {
        float tg = pn0 * g1[o * 4] + pn1 * g1[o * 4 + 1] + pn2 * g1[o * 4 + 2] + pn3 * g1[o * 4 + 3];
        gb[o] = fmaxf(scl[16 + o] * tg + scl[24 + o], 0.f);
      }
      float gv[8];
#pragma unroll
      for (int j = 0; j < 8; j++) {
        float t2 = 0.f;
#pragma unroll
        for (int o = 0; o < 8; o++) t2 += gb[o] * g2[j * 8 + o];
        gv[j] = wg * fmaxf(scl[32 + j] * t2 + scl[40 + j], 0.f);
      }
      uint4 pk;
      pk.x = pack2(gv[0], gv[1]); pk.y = pack2(gv[2], gv[3]);
      pk.z = pack2(gv[4], gv[5]); pk.w = pack2(gv[6], gv[7]);
      vecT[8 + k][px] = pk;
    }
  }
  __syncthreads();  // wtL visible; exm/den2 dead -> vecT[0..7] safe

  // fagg: 32 channels per half, all 9 k
  float fa[32];
#pragma unroll
  for (int c = 0; c < 32; c++) fa[c] = 0.f;
  const float* xf0 = xb + (size_t)(4 + half * 32) * HW_;
#pragma unroll
  for (int k = 0; k < 9; k++) {
    int di = k / 3 - 1, dj = k % 3 - 1;
    int hh = h + di, ww = w + dj;
    bool inb = ((unsigned)hh < (unsigned)H_) && ((unsigned)ww < (unsigned)W_);
    int ns = inb ? hh * W_ + ww : s;
    float wf = inb ? scratch[k * 128 + px] : 0.f;
    const float* xf = xf0 + ns;
#pragma unroll
    for (int c = 0; c < 32; c++) fa[c] += wf * xf[c * HW_];
  }
#pragma unroll
  for (int c = 0; c < 32; c += 8) {
    uint4 pk;
    pk.x = pack2(fa[c], fa[c + 1]);     pk.y = pack2(fa[c + 2], fa[c + 3]);
    pk.z = pack2(fa[c + 4], fa[c + 5]); pk.w = pack2(fa[c + 6], fa[c + 7]);
    vecT[half * 4 + (c >> 3)][px] = pk;
  }
  __syncthreads();

  // GEMM 128x64x160 (bf16 MFMA): nh = wave&1, mh = wave>>1
  int q = lane >> 4, r = lane & 15;
  int nh = wave & 1, mh = wave >> 1;
  short8 Bf[2][5];
#pragma unroll
  for (int nt = 0; nt < 2; nt++) {
    int n = (nh * 2 + nt) * 16 + r;
#pragma unroll
    for (int ks = 0; ks < 5; ks++) {
      int k0 = ks * 32 + q * 8;
      uint4 pk; pk.x = pk.y = pk.z = pk.w = 0u;
      if (k0 < 136) {
        float4 f0 = *reinterpret_cast<const float4*>(w_agg + n * 136 + k0);
        float4 f1 = *reinterpret_cast<const float4*>(w_agg + n * 136 + k0 + 4);
        pk.x = pack2(f0.x, f0.y); pk.y = pack2(f0.z, f0.w);
        pk.z = pack2(f1.x, f1.y); pk.w = pack2(f1.z, f1.w);
      }
      Bf[nt][ks] = *reinterpret_cast<short8*>(&pk);
    }
  }
  floatx4 acc4[4][2];
#pragma unroll
  for (int m = 0; m < 4; m++)
#pragma unroll
    for (int nt = 0; nt < 2; nt++) acc4[m][nt] = (floatx4){0.f, 0.f, 0.f, 0.f};
#pragma unroll
  for (int m = 0; m < 4; m++) {
    int pix = (mh * 4 + m) * 16 + r;
    short8 Af[5];
#pragma unroll
    for (int ks = 0; ks < 5; ks++) {
      int ch = ks * 4 + q;
      if (ch < 17)
        Af[ks] = *reinterpret_cast<const short8*>(&vecT[ch][pix]);
      else
        Af[ks] = (short8){0, 0, 0, 0, 0, 0, 0, 0};
    }
#pragma unroll
    for (int nt = 0; nt < 2; nt++)
#pragma unroll
      for (int ks = 0; ks < 5; ks++)
        acc4[m][nt] = __builtin_amdgcn_mfma_f32_16x16x32_bf16(Af[ks], Bf[nt][ks], acc4[m][nt], 0, 0, 0);
  }

  // stores (bf16 out_pre) + masked abn partial stats
  float aS[2] = {0.f, 0.f}, aQ[2] = {0.f, 0.f};
  unsigned short* out_pre = (unsigned short*)((char*)ws + OUTPRE_BYTE);
#pragma unroll
  for (int m = 0; m < 4; m++) {
    int srow = s0 + (mh * 4 + m) * 16 + q * 4;
    float4 mv = *reinterpret_cast<const float4*>(mb + srow);
    float m0 = (mv.x > 0.f) ? 1.f : 0.f, m1 = (mv.y > 0.f) ? 1.f : 0.f;
    float m2 = (mv.z > 0.f) ? 1.f : 0.f, m3 = (mv.w > 0.f) ? 1.f : 0.f;
#pragma unroll
    for (int nt = 0; nt < 2; nt++) {
      int ch = (nh * 2 + nt) * 16 + r;
      float o0 = acc4[m][nt][0], o1 = acc4[m][nt][1], o2 = acc4[m][nt][2], o3 = acc4[m][nt][3];
      aS[nt] += o0 * m0 + o1 * m1 + o2 * m2 + o3 * m3;
      aQ[nt] += o0 * o0 * m0 + o1 * o1 * m1 + o2 * o2 * m2 + o3 * o3 * m3;
      uint2 pk;
      pk.x = pack2(o0, o1); pk.y = pack2(o2, o3);
      *reinterpret_cast<uint2*>(out_pre + (size_t)(b * 64 + ch) * HW_ + srow) = pk;
    }
  }
  __syncthreads();
  float* rS = scratch;        // [4][32]
  float* rQ = scratch + 128;  // [4][32]
#pragma unroll
  for (int nt = 0; nt < 2; nt++) {
    float v1 = aS[nt], v2 = aQ[nt];
    v1 += __shfl_xor(v1, 16); v1 += __shfl_xor(v1, 32);
    v2 += __shfl_xor(v2, 16); v2 += __shfl_xor(v2, 32);
    if (lane < 16) { rS[wave * 32 + nt * 16 + lane] = v1; rQ[wave * 32 + nt * 16 + lane] = v2; }
  }
  __syncthreads();
  if (tid < 128) {
    float val;
    if (tid < 64) {
      int nh2 = tid >> 5, loc = tid & 31;
      val = rS[nh2 * 32 + loc] + rS[(2 + nh2) * 32 + loc];
    } else {
      int c2 = tid - 64;
      int nh2 = c2 >> 5, loc = c2 & 31;
      val = rQ[nh2 * 32 + loc] + rQ[(2 + nh2) * 32 + loc];
    }
    ws[ATOFF + tid * 1024 + bid] = val;
  }
  __threadfence();
  __syncthreads();
  if (tid == 0) {
    unsigned* cnt = (unsigned*)((char*)ws + CNTBYTE);
    islast = (atomicAdd(cnt + 2, 1u) == 1023u);
  }
  __syncthreads();
  if (islast) {
    __threadfence();
    for (int i = wave; i < 128; i += 4) {
      const float* src = ws + ATOFF + i * 1024;
      float v = 0.f;
#pragma unroll
      for (int j = 0; j < 16; j++) v += src[lane + j * 64];
      v = wred(v);
      if (lane == 0) ws[FINOFF + 50 + i] = v;
    }
  }
}

// ---------------- K4: abn apply + relu + center-mask zero -------------------
__global__ __launch_bounds__(256) void k_final(
    const float* __restrict__ mask, const float* __restrict__ abn_g,
    const float* __restrict__ abn_b, const float* __restrict__ ws,
    float* __restrict__ out) {
  __shared__ float sc[64], sh[64];
  if (threadIdx.x < 64) {
    int c = threadIdx.x;
    float n0 = fmaxf(ws[FINOFF + 33], 1.f);
    float mean = ws[FINOFF + 50 + c] / n0;
    float var = ws[FINOFF + 50 + 64 + c] / n0 - mean * mean;
    float s = abn_g[c] * rsqrtf(var + EPS);
    sc[c] = s; sh[c] = abn_b[c] - mean * s;
  }
  __syncthreads();
  const unsigned short* out_pre = (const unsigned short*)((const char*)ws + OUTPRE_BYTE);
  int i8 = (blockIdx.x * 256 + threadIdx.x) * 8;
  int c = (i8 >> 16) & 63;
  int b = i8 >> 22;
  int s = i8 & (HW_ - 1);
  uint4 v = *reinterpret_cast<const uint4*>(out_pre + i8);
  float4 ma = *reinterpret_cast<const float4*>(mask + (size_t)b * HW_ + s);
  float4 mb4 = *reinterpret_cast<const float4*>(mask + (size_t)b * HW_ + s + 4);
  float scc = sc[c], shc = sh[c];
  float4 o0, o1;
  o0.x = (ma.x > 0.f) ? fmaxf(bf2f((unsigned short)(v.x & 0xffff)) * scc + shc, 0.f) : 0.f;
  o0.y = (ma.y > 0.f) ? fmaxf(bf2f((unsigned short)(v.x >> 16)) * scc + shc, 0.f) : 0.f;
  o0.z = (ma.z > 0.f) ? fmaxf(bf2f((unsigned short)(v.y & 0xffff)) * scc + shc, 0.f) : 0.f;
  o0.w = (ma.w > 0.f) ? fmaxf(bf2f((unsigned short)(v.y >> 16)) * scc + shc, 0.f) : 0.f;
  o1.x = (mb4.x > 0.f) ? fmaxf(bf2f((unsigned short)(v.z & 0xffff)) * scc + shc, 0.f) : 0.f;
  o1.y = (mb4.y > 0.f) ? fmaxf(bf2f((unsigned short)(v.z >> 16)) * scc + shc, 0.f) : 0.f;
  o1.z = (mb4.z > 0.f) ? fmaxf(bf2f((unsigned short)(v.w & 0xffff)) * scc + shc, 0.f) : 0.f;
  o1.w = (mb4.w > 0.f) ? fmaxf(bf2f((unsigned short)(v.w >> 16)) * scc + shc, 0.f) : 0.f;
  *reinterpret_cast<float4*>(out + i8) = o0;
  *reinterpret_cast<float4*>(out + i8 + 4) = o1;
}

extern "C" void kernel_launch(void* const* d_in, const int* in_sizes, int n_in,
                              void* d_out, int out_size, void* d_ws, size_t ws_size,
                              hipStream_t stream) {
  const float* x      = (const float*)d_in[0];
  const float* mask   = (const float*)d_in[1];
  const float* w1     = (const float*)d_in[2];
  const float* bn1_g  = (const float*)d_in[3];
  const float* bn1_b  = (const float*)d_in[4];
  const float* w2     = (const float*)d_in[5];
  const float* b2     = (const float*)d_in[6];
  const float* g1     = (const float*)d_in[7];
  const float* gbn1_g = (const float*)d_in[8];
  const float* gbn1_b = (const float*)d_in[9];
  const float* g2     = (const float*)d_in[10];
  const float* gbn2_g = (const float*)d_in[11];
  const float* gbn2_b = (const float*)d_in[12];
  const float* w_agg  = (const float*)d_in[13];
  const float* abn_g  = (const float*)d_in[14];
  const float* abn_b  = (const float*)d_in[15];
  float* out = (float*)d_out;

  size_t need = (size_t)OUTPRE_BYTE + (size_t)NPIX * 64 * 2;
  if (ws_size < need) return;

  float* wsf = (float*)d_ws;
  hipMemsetAsync((char*)d_ws + CNTBYTE, 0, 256, stream);
  k_stats1<<<1024, 256, 0, stream>>>(x, mask, w1, g1, wsf);
  k_stats2<<<1024, 256, 0, stream>>>(x, mask, g1, gbn1_g, gbn1_b, g2, wsf);
  k_fused<<<1024, 256, 0, stream>>>(x, mask, w1, bn1_g, bn1_b, w2, b2, g1, g2,
                                    gbn1_g, gbn1_b, gbn2_g, gbn2_b, w_agg, wsf);
  k_final<<<4096, 256, 0, stream>>>(mask, abn_g, abn_b, wsf, out);
}

// Round 6
// 527.681 us; speedup vs baseline: 1.1399x; 1.1399x over previous
//
#include <hip/hip_runtime.h>

#define HW_ 65536
#define W_ 1024
#define H_ 64
#define C_ 68
#define NPIX 131072
#define EPS 1e-5f

// ws float layout:
//   P1 [34][1024] @ 0       stats1 partials (0-7 ta, 8-15 ta^2, 16-23 tg, 24-31 tg^2, 32 nmsel, 33 ncenter)
//   P2 [16][1024] @ 34816   stats2 partials
//   AT [128][1024] @ 51200  abn partials (0-63 sum, 64-127 sumsq)
//   FIN @ 182272            FIN1[34], FIN2[16] @+34, FINA[128] @+50
//   CNT @ byte 729856       3 uint ticket counters (memset 0 each launch)
//   out_pre bf16 @ byte 730112, NPIX*64 elements
#define P1OFF 0
#define P2OFF 34816
#define ATOFF 51200
#define FINOFF 182272
#define CNTBYTE 729856
#define OUTPRE_BYTE 730112

typedef __attribute__((ext_vector_type(8))) short short8;
typedef __attribute__((ext_vector_type(4))) float floatx4;

__device__ __forceinline__ unsigned short f2bf(float f) {
  unsigned u = __float_as_uint(f);
  u += 0x7fffu + ((u >> 16) & 1u);
  return (unsigned short)(u >> 16);
}
__device__ __forceinline__ unsigned pack2(float a, float b) {
  return (unsigned)f2bf(a) | ((unsigned)f2bf(b) << 16);
}
__device__ __forceinline__ float bf2f(unsigned short u) {
  return __uint_as_float(((unsigned)u) << 16);
}
__device__ __forceinline__ float wred(float v) {
  v += __shfl_xor(v, 1);  v += __shfl_xor(v, 2);  v += __shfl_xor(v, 4);
  v += __shfl_xor(v, 8);  v += __shfl_xor(v, 16); v += __shfl_xor(v, 32);
  return v;
}

// ---------------- K1: stats1 (k-split, 2 th/px) + last-block reduce ----------
// NOTE: no min-waves in launch_bounds — (256,4) forced VGPR=64 and spilled
// ~340 MB of scratch traffic (R5 post-mortem). Natural allocation ~124 VGPR
// already gives 4 waves/SIMD.
__global__ __launch_bounds__(256) void k_stats1(
    const float* __restrict__ x, const float* __restrict__ mask,
    const float* __restrict__ w1, const float* __restrict__ g1,
    float* __restrict__ ws) {
  __shared__ float red[136];
  __shared__ int islast;
  const int tid = threadIdx.x, bid = blockIdx.x;
  const int lane = tid & 63, wave = tid >> 6;

  const int tile = (bid & 7) * 128 + (bid >> 3);
  const int b = tile >> 9;
  const int s0 = (tile & 511) * 128;
  const int px = tid & 127;
  const int half = tid >> 7;
  const int s = s0 + px;
  const int h = s >> 10, w = s & (W_ - 1);
  const float* xb = x + (size_t)b * C_ * HW_;
  const float* mb = mask + (size_t)b * HW_;
  const int kbase = half ? 4 : 0;
  const int kcnt = half ? 5 : 4;

  float acc[34];
#pragma unroll
  for (int i = 0; i < 34; i++) acc[i] = 0.f;
  float xc0 = xb[s], xc1 = xb[HW_ + s], xc2 = xb[2 * HW_ + s], xc3 = xb[3 * HW_ + s];
  if (half == 0) acc[33] = (mb[s] > 0.f) ? 1.f : 0.f;
#pragma unroll
  for (int kk = 0; kk < 5; kk++) {
    if (kk < kcnt) {
      int k = kbase + kk;
      int di = k / 3 - 1, dj = k % 3 - 1;
      int hh = h + di, ww = w + dj;
      bool inb = ((unsigned)hh < (unsigned)H_) && ((unsigned)ww < (unsigned)W_);
      int ns = inb ? hh * W_ + ww : s;
      float mk = (inb && mb[ns] > 0.f) ? 1.f : 0.f;
      float pn0 = xb[ns] - xc0;
      float pn1 = xb[HW_ + ns] - xc1;
      float pn2 = xb[2 * HW_ + ns] - xc2;
      float pn3 = xb[3 * HW_ + ns] - xc3;
      acc[32] += mk;
#pragma unroll
      for (int o = 0; o < 8; o++) {
        float ta = pn0 * w1[o * 4] + pn1 * w1[o * 4 + 1] + pn2 * w1[o * 4 + 2] + pn3 * w1[o * 4 + 3];
        acc[o] += mk * ta; acc[8 + o] += mk * ta * ta;
        float tg = pn0 * g1[o * 4] + pn1 * g1[o * 4 + 1] + pn2 * g1[o * 4 + 2] + pn3 * g1[o * 4 + 3];
        acc[16 + o] += mk * tg; acc[24 + o] += mk * tg * tg;
      }
    }
  }
#pragma unroll
  for (int i = 0; i < 34; i++) {
    float r = wred(acc[i]);
    if (lane == 0) red[wave * 34 + i] = r;
  }
  __syncthreads();
  if (tid < 34)
    ws[P1OFF + tid * 1024 + bid] = red[tid] + red[34 + tid] + red[68 + tid] + red[102 + tid];
  __threadfence();
  __syncthreads();
  if (tid == 0) {
    unsigned* cnt = (unsigned*)((char*)ws + CNTBYTE);
    islast = (atomicAdd(cnt, 1u) == 1023u);
  }
  __syncthreads();
  if (islast) {
    __threadfence();
    for (int i = wave; i < 34; i += 4) {
      const float* src = ws + P1OFF + i * 1024;
      float v = 0.f;
#pragma unroll
      for (int j = 0; j < 16; j++) v += src[lane + j * 64];
      v = wred(v);
      if (lane == 0) ws[FINOFF + i] = v;
    }
  }
}

// ---------------- K2: stats2 (k-split) + last-block reduce ------------------
__global__ __launch_bounds__(256) void k_stats2(
    const float* __restrict__ x, const float* __restrict__ mask,
    const float* __restrict__ g1, const float* __restrict__ gbn1_g,
    const float* __restrict__ gbn1_b, const float* __restrict__ g2,
    float* __restrict__ ws) {
  __shared__ float scl[16];
  __shared__ float red[64];
  __shared__ int islast;
  const int tid = threadIdx.x, bid = blockIdx.x;
  const int lane = tid & 63, wave = tid >> 6;

  if (tid < 8) {
    float n = fmaxf(ws[FINOFF + 32], 1.f);
    float mean = ws[FINOFF + 16 + tid] / n;
    float var = ws[FINOFF + 24 + tid] / n - mean * mean;
    float sv = gbn1_g[tid] * rsqrtf(var + EPS);
    scl[tid] = sv;
    scl[8 + tid] = gbn1_b[tid] - mean * sv;
  }
  __syncthreads();

  const int tile = (bid & 7) * 128 + (bid >> 3);
  const int b = tile >> 9;
  const int s0 = (tile & 511) * 128;
  const int px = tid & 127;
  const int half = tid >> 7;
  const int s = s0 + px;
  const int h = s >> 10, w = s & (W_ - 1);
  const float* xb = x + (size_t)b * C_ * HW_;
  const float* mb = mask + (size_t)b * HW_;
  const int kbase = half ? 4 : 0;
  const int kcnt = half ? 5 : 4;

  float acc[16];
#pragma unroll
  for (int i = 0; i < 16; i++) acc[i] = 0.f;
  float xc0 = xb[s], xc1 = xb[HW_ + s], xc2 = xb[2 * HW_ + s], xc3 = xb[3 * HW_ + s];
#pragma unroll
  for (int kk = 0; kk < 5; kk++) {
    if (kk < kcnt) {
      int k = kbase + kk;
      int di = k / 3 - 1, dj = k % 3 - 1;
      int hh = h + di, ww = w + dj;
      bool inb = ((unsigned)hh < (unsigned)H_) && ((unsigned)ww < (unsigned)W_);
      int ns = inb ? hh * W_ + ww : s;
      float mk = (inb && mb[ns] > 0.f) ? 1.f : 0.f;
      float pn0 = xb[ns] - xc0;
      float pn1 = xb[HW_ + ns] - xc1;
      float pn2 = xb[2 * HW_ + ns] - xc2;
      float pn3 = xb[3 * HW_ + ns] - xc3;
      float gb[8];
#pragma unroll
      for (int o = 0; o < 8; o++) {
        float tg = pn0 * g1[o * 4] + pn1 * g1[o * 4 + 1] + pn2 * g1[o * 4 + 2] + pn3 * g1[o * 4 + 3];
        gb[o] = fmaxf(scl[o] * tg + scl[8 + o], 0.f);
      }
#pragma unroll
      for (int j = 0; j < 8; j++) {
        float t2 = 0.f;
#pragma unroll
        for (int o = 0; o < 8; o++) t2 += gb[o] * g2[j * 8 + o];
        acc[j] += mk * t2; acc[8 + j] += mk * t2 * t2;
      }
    }
  }
#pragma unroll
  for (int i = 0; i < 16; i++) {
    float r = wred(acc[i]);
    if (lane == 0) red[wave * 16 + i] = r;
  }
  __syncthreads();
  if (tid < 16)
    ws[P2OFF + tid * 1024 + bid] = red[tid] + red[16 + tid] + red[32 + tid] + red[48 + tid];
  __threadfence();
  __syncthreads();
  if (tid == 0) {
    unsigned* cnt = (unsigned*)((char*)ws + CNTBYTE);
    islast = (atomicAdd(cnt + 1, 1u) == 1023u);
  }
  __syncthreads();
  if (islast) {
    __threadfence();
    for (int i = wave; i < 16; i += 4) {
      const float* src = ws + P2OFF + i * 1024;
      float v = 0.f;
#pragma unroll
      for (int j = 0; j < 16; j++) v += src[lane + j * 64];
      v = wred(v);
      if (lane == 0) ws[FINOFF + 34 + i] = v;
    }
  }
}

// --------- K3: fused vec build (k-split softmax) + MFMA GEMM + abn partials -
__global__ __launch_bounds__(256) void k_fused(
    const float* __restrict__ x, const float* __restrict__ mask,
    const float* __restrict__ w1, const float* __restrict__ bn1_g,
    const float* __restrict__ bn1_b, const float* __restrict__ w2,
    const float* __restrict__ b2, const float* __restrict__ g1,
    const float* __restrict__ g2, const float* __restrict__ gbn1_g,
    const float* __restrict__ gbn1_b, const float* __restrict__ gbn2_g,
    const float* __restrict__ gbn2_b, const float* __restrict__ w_agg,
    float* __restrict__ ws) {
  // LDS: vecT 34816 | scratch 4608 (wtL / rS+rQ) | scl 192
  __shared__ __align__(16) char smem[34816 + 4608 + 192];
  uint4(*vecT)[128] = (uint4(*)[128])smem;
  float* scratch = (float*)(smem + 34816);
  float* scl = (float*)(smem + 34816 + 4608);  // sA@0 hA@8 sG1@16 hG1@24 sG2@32 hG2@40
  float* exm = (float*)smem;                   // [2][128] aliases vecT[0..1] (dead before fagg)
  float* den2 = (float*)(smem + 1024);
  __shared__ int islast;

  const int tid = threadIdx.x, bid = blockIdx.x;
  const int lane = tid & 63, wave = tid >> 6;

  if (tid < 24) {
    int o = tid & 7;
    float n = fmaxf(ws[FINOFF + 32], 1.f);
    float sum, sum2, gma, bta;
    if (tid < 8)       { sum = ws[FINOFF + o];      sum2 = ws[FINOFF + 8 + o];  gma = bn1_g[o];  bta = bn1_b[o]; }
    else if (tid < 16) { sum = ws[FINOFF + 16 + o]; sum2 = ws[FINOFF + 24 + o]; gma = gbn1_g[o]; bta = gbn1_b[o]; }
    else               { sum = ws[FINOFF + 34 + o]; sum2 = ws[FINOFF + 42 + o]; gma = gbn2_g[o]; bta = gbn2_b[o]; }
    float mean = sum / n, var = sum2 / n - mean * mean;
    float sv = gma * rsqrtf(var + EPS);
    scl[(tid >> 3) * 16 + o] = sv;
    scl[(tid >> 3) * 16 + 8 + o] = bta - mean * sv;
  }
  __syncthreads();

  const int tile = (bid & 7) * 128 + (bid >> 3);
  const int b = tile >> 9;
  const int s0 = (tile & 511) * 128;
  const int px = tid & 127;
  const int half = tid >> 7;  // wave-uniform
  const int s = s0 + px;
  const int h = s >> 10, w = s & (W_ - 1);
  const float* xb = x + (size_t)b * C_ * HW_;
  const float* mb = mask + (size_t)b * HW_;
  const int kbase = half ? 4 : 0;
  const int kcnt = half ? 5 : 4;

  float xc0 = xb[s], xc1 = xb[HW_ + s], xc2 = xb[2 * HW_ + s], xc3 = xb[3 * HW_ + s];
  float b2v = b2[0];
  float evL[5], mkL[5]; int nsL[5];
  float mx = -1e30f;
#pragma unroll
  for (int kk = 0; kk < 5; kk++) {
    if (kk < kcnt) {
      int k = kbase + kk;
      int di = k / 3 - 1, dj = k % 3 - 1;
      int hh = h + di, ww = w + dj;
      bool inb = ((unsigned)hh < (unsigned)H_) && ((unsigned)ww < (unsigned)W_);
      int ns = inb ? hh * W_ + ww : s;
      nsL[kk] = ns;
      float mk = (inb && mb[ns] > 0.f) ? 1.f : 0.f;
      mkL[kk] = mk;
      float pn0 = xb[ns] - xc0;
      float pn1 = xb[HW_ + ns] - xc1;
      float pn2 = xb[2 * HW_ + ns] - xc2;
      float pn3 = xb[3 * HW_ + ns] - xc3;
      float accw = 0.f;
#pragma unroll
      for (int o = 0; o < 8; o++) {
        float ta = pn0 * w1[o * 4] + pn1 * w1[o * 4 + 1] + pn2 * w1[o * 4 + 2] + pn3 * w1[o * 4 + 3];
        accw += fmaxf(scl[o] * ta + scl[8 + o], 0.f) * w2[o];
      }
      float wp = mk * (accw + b2v);
      evL[kk] = wp;
      mx = fmaxf(mx, wp);
    }
  }
  exm[half * 128 + px] = mx;
  __syncthreads();
  float gmx = fmaxf(exm[px], exm[128 + px]);
  float dp = 0.f;
#pragma unroll
  for (int kk = 0; kk < 5; kk++)
    if (kk < kcnt) { evL[kk] = __expf(evL[kk] - gmx); dp += evL[kk]; }
  den2[half * 128 + px] = dp;
  __syncthreads();
  float inv = 1.f / (den2[px] + den2[128 + px]);

  // own k's: wt -> wtL(scratch), weighted g -> vecT[8+k]
#pragma unroll
  for (int kk = 0; kk < 5; kk++) {
    if (kk < kcnt) {
      int k = kbase + kk;
      float wt = evL[kk] * inv;
      scratch[k * 128 + px] = wt;
      int ns = nsL[kk];
      float wg = wt * mkL[kk];
      float pn0 = xb[ns] - xc0;
      float pn1 = xb[HW_ + ns] - xc1;
      float pn2 = xb[2 * HW_ + ns] - xc2;
      float pn3 = xb[3 * HW_ + ns] - xc3;
      float gb[8];
#pragma unroll
      for (int o = 0; o < 8; o++) {
        float tg = pn0 * g1[o * 4] + pn1 * g1[o * 4 + 1] + pn2 * g1[o * 4 + 2] + pn3 * g1[o * 4 + 3];
        gb[o] = fmaxf(scl[16 + o] * tg + scl[24 + o], 0.f);
      }
      float gv[8];
#pragma unroll
      for (int j = 0; j < 8; j++) {
        float t2 = 0.f;
#pragma unroll
        for (int o = 0; o < 8; o++) t2 += gb[o] * g2[j * 8 + o];
        gv[j] = wg * fmaxf(scl[32 + j] * t2 + scl[40 + j], 0.f);
      }
      uint4 pk;
      pk.x = pack2(gv[0], gv[1]); pk.y = pack2(gv[2], gv[3]);
      pk.z = pack2(gv[4], gv[5]); pk.w = pack2(gv[6], gv[7]);
      vecT[8 + k][px] = pk;
    }
  }
  __syncthreads();  // wtL visible; exm/den2 dead -> vecT[0..7] safe

  // fagg: 32 channels per half, all 9 k
  float fa[32];
#pragma unroll
  for (int c = 0; c < 32; c++) fa[c] = 0.f;
  const float* xf0 = xb + (size_t)(4 + half * 32) * HW_;
#pragma unroll
  for (int k = 0; k < 9; k++) {
    int di = k / 3 - 1, dj = k % 3 - 1;
    int hh = h + di, ww = w + dj;
    bool inb = ((unsigned)hh < (unsigned)H_) && ((unsigned)ww < (unsigned)W_);
    int ns = inb ? hh * W_ + ww : s;
    float wf = inb ? scratch[k * 128 + px] : 0.f;
    const float* xf = xf0 + ns;
#pragma unroll
    for (int c = 0; c < 32; c++) fa[c] += wf * xf[c * HW_];
  }
#pragma unroll
  for (int c = 0; c < 32; c += 8) {
    uint4 pk;
    pk.x = pack2(fa[c], fa[c + 1]);     pk.y = pack2(fa[c + 2], fa[c + 3]);
    pk.z = pack2(fa[c + 4], fa[c + 5]); pk.w = pack2(fa[c + 6], fa[c + 7]);
    vecT[half * 4 + (c >> 3)][px] = pk;
  }
  __syncthreads();

  // GEMM 128x64x160 (bf16 MFMA): nh = wave&1, mh = wave>>1
  int q = lane >> 4, r = lane & 15;
  int nh = wave & 1, mh = wave >> 1;
  short8 Bf[2][5];
#pragma unroll
  for (int nt = 0; nt < 2; nt++) {
    int n = (nh * 2 + nt) * 16 + r;
#pragma unroll
    for (int ks = 0; ks < 5; ks++) {
      int k0 = ks * 32 + q * 8;
      uint4 pk; pk.x = pk.y = pk.z = pk.w = 0u;
      if (k0 < 136) {
        float4 f0 = *reinterpret_cast<const float4*>(w_agg + n * 136 + k0);
        float4 f1 = *reinterpret_cast<const float4*>(w_agg + n * 136 + k0 + 4);
        pk.x = pack2(f0.x, f0.y); pk.y = pack2(f0.z, f0.w);
        pk.z = pack2(f1.x, f1.y); pk.w = pack2(f1.z, f1.w);
      }
      Bf[nt][ks] = *reinterpret_cast<short8*>(&pk);
    }
  }
  floatx4 acc4[4][2];
#pragma unroll
  for (int m = 0; m < 4; m++)
#pragma unroll
    for (int nt = 0; nt < 2; nt++) acc4[m][nt] = (floatx4){0.f, 0.f, 0.f, 0.f};
#pragma unroll
  for (int m = 0; m < 4; m++) {
    int pix = (mh * 4 + m) * 16 + r;
    short8 Af[5];
#pragma unroll
    for (int ks = 0; ks < 5; ks++) {
      int ch = ks * 4 + q;
      if (ch < 17)
        Af[ks] = *reinterpret_cast<const short8*>(&vecT[ch][pix]);
      else
        Af[ks] = (short8){0, 0, 0, 0, 0, 0, 0, 0};
    }
#pragma unroll
    for (int nt = 0; nt < 2; nt++)
#pragma unroll
      for (int ks = 0; ks < 5; ks++)
        acc4[m][nt] = __builtin_amdgcn_mfma_f32_16x16x32_bf16(Af[ks], Bf[nt][ks], acc4[m][nt], 0, 0, 0);
  }

  // stores (bf16 out_pre) + masked abn partial stats
  float aS[2] = {0.f, 0.f}, aQ[2] = {0.f, 0.f};
  unsigned short* out_pre = (unsigned short*)((char*)ws + OUTPRE_BYTE);
#pragma unroll
  for (int m = 0; m < 4; m++) {
    int srow = s0 + (mh * 4 + m) * 16 + q * 4;
    float4 mv = *reinterpret_cast<const float4*>(mb + srow);
    float m0 = (mv.x > 0.f) ? 1.f : 0.f, m1 = (mv.y > 0.f) ? 1.f : 0.f;
    float m2 = (mv.z > 0.f) ? 1.f : 0.f, m3 = (mv.w > 0.f) ? 1.f : 0.f;
#pragma unroll
    for (int nt = 0; nt < 2; nt++) {
      int ch = (nh * 2 + nt) * 16 + r;
      float o0 = acc4[m][nt][0], o1 = acc4[m][nt][1], o2 = acc4[m][nt][2], o3 = acc4[m][nt][3];
      aS[nt] += o0 * m0 + o1 * m1 + o2 * m2 + o3 * m3;
      aQ[nt] += o0 * o0 * m0 + o1 * o1 * m1 + o2 * o2 * m2 + o3 * o3 * m3;
      uint2 pk;
      pk.x = pack2(o0, o1); pk.y = pack2(o2, o3);
      *reinterpret_cast<uint2*>(out_pre + (size_t)(b * 64 + ch) * HW_ + srow) = pk;
    }
  }
  __syncthreads();
  float* rS = scratch;        // [4][32]
  float* rQ = scratch + 128;  // [4][32]
#pragma unroll
  for (int nt = 0; nt < 2; nt++) {
    float v1 = aS[nt], v2 = aQ[nt];
    v1 += __shfl_xor(v1, 16); v1 += __shfl_xor(v1, 32);
    v2 += __shfl_xor(v2, 16); v2 += __shfl_xor(v2, 32);
    if (lane < 16) { rS[wave * 32 + nt * 16 + lane] = v1; rQ[wave * 32 + nt * 16 + lane] = v2; }
  }
  __syncthreads();
  if (tid < 128) {
    float val;
    if (tid < 64) {
      int nh2 = tid >> 5, loc = tid & 31;
      val = rS[nh2 * 32 + loc] + rS[(2 + nh2) * 32 + loc];
    } else {
      int c2 = tid - 64;
      int nh2 = c2 >> 5, loc = c2 & 31;
      val = rQ[nh2 * 32 + loc] + rQ[(2 + nh2) * 32 + loc];
    }
    ws[ATOFF + tid * 1024 + bid] = val;
  }
  __threadfence();
  __syncthreads();
  if (tid == 0) {
    unsigned* cnt = (unsigned*)((char*)ws + CNTBYTE);
    islast = (atomicAdd(cnt + 2, 1u) == 1023u);
  }
  __syncthreads();
  if (islast) {
    __threadfence();
    for (int i = wave; i < 128; i += 4) {
      const float* src = ws + ATOFF + i * 1024;
      float v = 0.f;
#pragma unroll
      for (int j = 0; j < 16; j++) v += src[lane + j * 64];
      v = wred(v);
      if (lane == 0) ws[FINOFF + 50 + i] = v;
    }
  }
}

// ---------------- K4: abn apply + relu + center-mask zero -------------------
__global__ __launch_bounds__(256) void k_final(
    const float* __restrict__ mask, const float* __restrict__ abn_g,
    const float* __restrict__ abn_b, const float* __restrict__ ws,
    float* __restrict__ out) {
  __shared__ float sc[64], sh[64];
  if (threadIdx.x < 64) {
    int c = threadIdx.x;
    float n0 = fmaxf(ws[FINOFF + 33], 1.f);
    float mean = ws[FINOFF + 50 + c] / n0;
    float var = ws[FINOFF + 50 + 64 + c] / n0 - mean * mean;
    float s = abn_g[c] * rsqrtf(var + EPS);
    sc[c] = s; sh[c] = abn_b[c] - mean * s;
  }
  __syncthreads();
  const unsigned short* out_pre = (const unsigned short*)((const char*)ws + OUTPRE_BYTE);
  int i8 = (blockIdx.x * 256 + threadIdx.x) * 8;
  int c = (i8 >> 16) & 63;
  int b = i8 >> 22;
  int s = i8 & (HW_ - 1);
  uint4 v = *reinterpret_cast<const uint4*>(out_pre + i8);
  float4 ma = *reinterpret_cast<const float4*>(mask + (size_t)b * HW_ + s);
  float4 mb4 = *reinterpret_cast<const float4*>(mask + (size_t)b * HW_ + s + 4);
  float scc = sc[c], shc = sh[c];
  float4 o0, o1;
  o0.x = (ma.x > 0.f) ? fmaxf(bf2f((unsigned short)(v.x & 0xffff)) * scc + shc, 0.f) : 0.f;
  o0.y = (ma.y > 0.f) ? fmaxf(bf2f((unsigned short)(v.x >> 16)) * scc + shc, 0.f) : 0.f;
  o0.z = (ma.z > 0.f) ? fmaxf(bf2f((unsigned short)(v.y & 0xffff)) * scc + shc, 0.f) : 0.f;
  o0.w = (ma.w > 0.f) ? fmaxf(bf2f((unsigned short)(v.y >> 16)) * scc + shc, 0.f) : 0.f;
  o1.x = (mb4.x > 0.f) ? fmaxf(bf2f((unsigned short)(v.z & 0xffff)) * scc + shc, 0.f) : 0.f;
  o1.y = (mb4.y > 0.f) ? fmaxf(bf2f((unsigned short)(v.z >> 16)) * scc + shc, 0.f) : 0.f;
  o1.z = (mb4.z > 0.f) ? fmaxf(bf2f((unsigned short)(v.w & 0xffff)) * scc + shc, 0.f) : 0.f;
  o1.w = (mb4.w > 0.f) ? fmaxf(bf2f((unsigned short)(v.w >> 16)) * scc + shc, 0.f) : 0.f;
  *reinterpret_cast<float4*>(out + i8) = o0;
  *reinterpret_cast<float4*>(out + i8 + 4) = o1;
}

extern "C" void kernel_launch(void* const* d_in, const int* in_sizes, int n_in,
                              void* d_out, int out_size, void* d_ws, size_t ws_size,
                              hipStream_t stream) {
  const float* x      = (const float*)d_in[0];
  const float* mask   = (const float*)d_in[1];
  const float* w1     = (const float*)d_in[2];
  const float* bn1_g  = (const float*)d_in[3];
  const float* bn1_b  = (const float*)d_in[4];
  const float* w2     = (const float*)d_in[5];
  const float* b2     = (const float*)d_in[6];
  const float* g1     = (const float*)d_in[7];
  const float* gbn1_g = (const float*)d_in[8];
  const float* gbn1_b = (const float*)d_in[9];
  const float* g2     = (const float*)d_in[10];
  const float* gbn2_g = (const float*)d_in[11];
  const float* gbn2_b = (const float*)d_in[12];
  const float* w_agg  = (const float*)d_in[13];
  const float* abn_g  = (const float*)d_in[14];
  const float* abn_b  = (const float*)d_in[15];
  float* out = (float*)d_out;

  size_t need = (size_t)OUTPRE_BYTE + (size_t)NPIX * 64 * 2;
  if (ws_size < need) return;

  float* wsf = (float*)d_ws;
  hipMemsetAsync((char*)d_ws + CNTBYTE, 0, 256, stream);
  k_stats1<<<1024, 256, 0, stream>>>(x, mask, w1, g1, wsf);
  k_stats2<<<1024, 256, 0, stream>>>(x, mask, g1, gbn1_g, gbn1_b, g2, wsf);
  k_fused<<<1024, 256, 0, stream>>>(x, mask, w1, bn1_g, bn1_b, w2, b2, g1, g2,
                                    gbn1_g, gbn1_b, gbn2_g, gbn2_b, w_agg, wsf);
  k_final<<<4096, 256, 0, stream>>>(mask, abn_g, abn_b, wsf, out);
}

// Round 7
// 307.406 us; speedup vs baseline: 1.9567x; 1.7166x over previous
//
#include <hip/hip_runtime.h>

#define HW_ 65536
#define W_ 1024
#define H_ 64
#define C_ 68
#define NPIX 131072
#define EPS 1e-5f

// ws float layout (atomic slots strided 16 floats = 64 B to parallelize L2 atomic chains):
//   MOM  slot i @ ws[i*16],        i=0..15 : S0-3, M00,M01,M02,M03,M11,M12,M13,M22,M23,M33, n_msel, n_center
//   ST2  slot j @ ws[256 + j*16],  j=0..15 : gbn2 sum[8], sumsq[8]
//   AT   slot c @ ws[512 + c*16],  c=0..127: abn sum[64], sumsq[64]
//   out_pre bf16 @ byte 16384, NPIX*64 elements
#define ST2OFF 256
#define ATOFF 512
#define OUTPRE_BYTE 16384

typedef __attribute__((ext_vector_type(8))) short short8;
typedef __attribute__((ext_vector_type(4))) float floatx4;

__device__ __forceinline__ unsigned short f2bf(float f) {
  unsigned u = __float_as_uint(f);
  u += 0x7fffu + ((u >> 16) & 1u);
  return (unsigned short)(u >> 16);
}
__device__ __forceinline__ unsigned pack2(float a, float b) {
  return (unsigned)f2bf(a) | ((unsigned)f2bf(b) << 16);
}
__device__ __forceinline__ float bf2f(unsigned short u) {
  return __uint_as_float(((unsigned)u) << 16);
}
__device__ __forceinline__ float wred(float v) {
  v += __shfl_xor(v, 1);  v += __shfl_xor(v, 2);  v += __shfl_xor(v, 4);
  v += __shfl_xor(v, 8);  v += __shfl_xor(v, 16); v += __shfl_xor(v, 32);
  return v;
}

// ---- K1: pn moment stats (S, M, counts). 4 th/px (wave = k-subset), 2048 blocks.
__global__ __launch_bounds__(256) void k_stats1(
    const float* __restrict__ x, const float* __restrict__ mask,
    float* __restrict__ ws) {
  __shared__ float red[4][16];
  const int tid = threadIdx.x, bid = blockIdx.x;
  const int lane = tid & 63, wave = tid >> 6;
  const int seg = (bid & 7) * 256 + (bid >> 3);  // XCD-contiguous over 2048
  const int sg = seg * 64 + lane;
  const int b = sg >> 16, s = sg & (HW_ - 1);
  const int h = s >> 10, w = s & (W_ - 1);
  const float* xb = x + (size_t)b * C_ * HW_;
  const float* mb = mask + (size_t)b * HW_;

  float acc[16];
#pragma unroll
  for (int i = 0; i < 16; i++) acc[i] = 0.f;
  float xc0 = xb[s], xc1 = xb[HW_ + s], xc2 = xb[2 * HW_ + s], xc3 = xb[3 * HW_ + s];
  if (wave == 0) acc[15] = (mb[s] > 0.f) ? 1.f : 0.f;

  for (int k = wave; k < 9; k += 4) {
    int di = k / 3 - 1, dj = k % 3 - 1;
    int hh = h + di, ww = w + dj;
    bool inb = ((unsigned)hh < (unsigned)H_) && ((unsigned)ww < (unsigned)W_);
    int ns = inb ? hh * W_ + ww : s;
    float mk = (inb && mb[ns] > 0.f) ? 1.f : 0.f;
    float p0 = xb[ns] - xc0;
    float p1 = xb[HW_ + ns] - xc1;
    float p2 = xb[2 * HW_ + ns] - xc2;
    float p3 = xb[3 * HW_ + ns] - xc3;
    float q0 = mk * p0, q1 = mk * p1, q2 = mk * p2, q3 = mk * p3;
    acc[0] += q0; acc[1] += q1; acc[2] += q2; acc[3] += q3;
    acc[4] += q0 * p0; acc[5] += q0 * p1; acc[6] += q0 * p2; acc[7] += q0 * p3;
    acc[8] += q1 * p1; acc[9] += q1 * p2; acc[10] += q1 * p3;
    acc[11] += q2 * p2; acc[12] += q2 * p3;
    acc[13] += q3 * p3;
    acc[14] += mk;
  }
#pragma unroll
  for (int i = 0; i < 16; i++) {
    float r = wred(acc[i]);
    if (lane == 0) red[wave][i] = r;
  }
  __syncthreads();
  if (tid < 16)
    atomicAdd(&ws[tid * 16], red[0][tid] + red[1][tid] + red[2][tid] + red[3][tid]);
}

// ---- K2: gbn2 input stats: relu(gbn1(pn@g1^T)) @ g2^T. 4 th/px, 2048 blocks.
__global__ __launch_bounds__(256) void k_stats2(
    const float* __restrict__ x, const float* __restrict__ mask,
    const float* __restrict__ g1, const float* __restrict__ gbn1_g,
    const float* __restrict__ gbn1_b, const float* __restrict__ g2,
    float* __restrict__ ws) {
  __shared__ float scl[16];
  __shared__ float red[4][16];
  const int tid = threadIdx.x, bid = blockIdx.x;
  const int lane = tid & 63, wave = tid >> 6;

  if (tid < 8) {  // finalize gbn1 affine from moments
    int o = tid;
    float n = fmaxf(ws[224], 1.f);  // slot 14
    const float* wv = g1 + o * 4;
    float w0 = wv[0], w1v = wv[1], w2v = wv[2], w3v = wv[3];
    float sum = w0 * ws[0] + w1v * ws[16] + w2v * ws[32] + w3v * ws[48];
    float quad = w0 * (w0 * ws[64] + 2.f * (w1v * ws[80] + w2v * ws[96] + w3v * ws[112]))
               + w1v * (w1v * ws[128] + 2.f * (w2v * ws[144] + w3v * ws[160]))
               + w2v * (w2v * ws[176] + 2.f * w3v * ws[192])
               + w3v * w3v * ws[208];
    float mean = sum / n, var = quad / n - mean * mean;
    float sv = gbn1_g[o] * rsqrtf(var + EPS);
    scl[o] = sv; scl[8 + o] = gbn1_b[o] - mean * sv;
  }
  __syncthreads();

  const int seg = (bid & 7) * 256 + (bid >> 3);
  const int sg = seg * 64 + lane;
  const int b = sg >> 16, s = sg & (HW_ - 1);
  const int h = s >> 10, w = s & (W_ - 1);
  const float* xb = x + (size_t)b * C_ * HW_;
  const float* mb = mask + (size_t)b * HW_;

  float acc[16];
#pragma unroll
  for (int i = 0; i < 16; i++) acc[i] = 0.f;
  float xc0 = xb[s], xc1 = xb[HW_ + s], xc2 = xb[2 * HW_ + s], xc3 = xb[3 * HW_ + s];

  for (int k = wave; k < 9; k += 4) {
    int di = k / 3 - 1, dj = k % 3 - 1;
    int hh = h + di, ww = w + dj;
    bool inb = ((unsigned)hh < (unsigned)H_) && ((unsigned)ww < (unsigned)W_);
    int ns = inb ? hh * W_ + ww : s;
    float mk = (inb && mb[ns] > 0.f) ? 1.f : 0.f;
    float pn0 = xb[ns] - xc0;
    float pn1 = xb[HW_ + ns] - xc1;
    float pn2 = xb[2 * HW_ + ns] - xc2;
    float pn3 = xb[3 * HW_ + ns] - xc3;
    float gb[8];
#pragma unroll
    for (int o = 0; o < 8; o++) {
      float tg = pn0 * g1[o * 4] + pn1 * g1[o * 4 + 1] + pn2 * g1[o * 4 + 2] + pn3 * g1[o * 4 + 3];
      gb[o] = fmaxf(scl[o] * tg + scl[8 + o], 0.f);
    }
#pragma unroll
    for (int j = 0; j < 8; j++) {
      float t2 = 0.f;
#pragma unroll
      for (int o = 0; o < 8; o++) t2 += gb[o] * g2[j * 8 + o];
      acc[j] += mk * t2; acc[8 + j] += mk * t2 * t2;
    }
  }
#pragma unroll
  for (int i = 0; i < 16; i++) {
    float r = wred(acc[i]);
    if (lane == 0) red[wave][i] = r;
  }
  __syncthreads();
  if (tid < 16)
    atomicAdd(&ws[ST2OFF + tid * 16], red[0][tid] + red[1][tid] + red[2][tid] + red[3][tid]);
}

// ---- K3: R2-core fused kernel: 256 px/block, 1 th/px, vec build + MFMA GEMM.
__global__ __launch_bounds__(256) void k_fused(
    const float* __restrict__ x, const float* __restrict__ mask,
    const float* __restrict__ w1, const float* __restrict__ bn1_g,
    const float* __restrict__ bn1_b, const float* __restrict__ w2,
    const float* __restrict__ b2, const float* __restrict__ g1,
    const float* __restrict__ gbn1_g, const float* __restrict__ gbn1_b,
    const float* __restrict__ g2, const float* __restrict__ gbn2_g,
    const float* __restrict__ gbn2_b, const float* __restrict__ w_agg,
    float* __restrict__ ws) {
  __shared__ uint4 vecA[17][256];
  __shared__ float sA[8], hA[8], sG1[8], hG1[8], sG2[8], hG2[8];
  const int tid = threadIdx.x;

  if (tid < 24) {
    int o = tid & 7;
    float n = fmaxf(ws[224], 1.f);
    float sv, sft;
    if (tid < 16) {
      const float* wv = (tid < 8) ? (w1 + o * 4) : (g1 + o * 4);
      float w0 = wv[0], w1v = wv[1], w2v = wv[2], w3v = wv[3];
      float sum = w0 * ws[0] + w1v * ws[16] + w2v * ws[32] + w3v * ws[48];
      float quad = w0 * (w0 * ws[64] + 2.f * (w1v * ws[80] + w2v * ws[96] + w3v * ws[112]))
                 + w1v * (w1v * ws[128] + 2.f * (w2v * ws[144] + w3v * ws[160]))
                 + w2v * (w2v * ws[176] + 2.f * w3v * ws[192])
                 + w3v * w3v * ws[208];
      float gma = (tid < 8) ? bn1_g[o] : gbn1_g[o];
      float bta = (tid < 8) ? bn1_b[o] : gbn1_b[o];
      float mean = sum / n, var = quad / n - mean * mean;
      sv = gma * rsqrtf(var + EPS); sft = bta - mean * sv;
    } else {
      float sum = ws[ST2OFF + o * 16], sum2 = ws[ST2OFF + (8 + o) * 16];
      float mean = sum / n, var = sum2 / n - mean * mean;
      sv = gbn2_g[o] * rsqrtf(var + EPS); sft = gbn2_b[o] - mean * sv;
    }
    if (tid < 8)       { sA[o] = sv;  hA[o] = sft; }
    else if (tid < 16) { sG1[o] = sv; hG1[o] = sft; }
    else               { sG2[o] = sv; hG2[o] = sft; }
  }
  __syncthreads();

  int tile = (blockIdx.x & 7) * 64 + (blockIdx.x >> 3);  // XCD-contiguous over 512
  int p0 = tile * 256;
  int p = p0 + tid;
  int b = p >> 16, s = p & (HW_ - 1);
  int h = s >> 10, w = s & (W_ - 1);
  const float* xb = x + (size_t)b * C_ * HW_;
  const float* mb = mask + (size_t)b * HW_;
  float xc0 = xb[s], xc1 = xb[HW_ + s], xc2 = xb[2 * HW_ + s], xc3 = xb[3 * HW_ + s];
  float b2v = b2[0];

  float ev[9], mkv[9], ibv[9]; int nsv[9];
  float mx = -1e30f;
#pragma unroll
  for (int k = 0; k < 9; k++) {
    int di = k / 3 - 1, dj = k % 3 - 1;
    int hh = h + di, ww = w + dj;
    bool inb = ((unsigned)hh < (unsigned)H_) && ((unsigned)ww < (unsigned)W_);
    int ns = inb ? hh * W_ + ww : s;
    nsv[k] = ns;
    ibv[k] = inb ? 1.f : 0.f;
    float mval = mb[ns];
    float mk = (inb && mval > 0.f) ? 1.f : 0.f;
    mkv[k] = mk;
    float pn0 = xb[ns] - xc0;
    float pn1 = xb[HW_ + ns] - xc1;
    float pn2 = xb[2 * HW_ + ns] - xc2;
    float pn3 = xb[3 * HW_ + ns] - xc3;
    float accw = 0.f;
#pragma unroll
    for (int o = 0; o < 8; o++) {
      float ta = pn0 * w1[o * 4] + pn1 * w1[o * 4 + 1] + pn2 * w1[o * 4 + 2] + pn3 * w1[o * 4 + 3];
      accw += fmaxf(sA[o] * ta + hA[o], 0.f) * w2[o];
    }
    float wp = mk * (accw + b2v);
    ev[k] = wp;
    mx = fmaxf(mx, wp);
  }
  float den = 0.f;
#pragma unroll
  for (int k = 0; k < 9; k++) { ev[k] = __expf(ev[k] - mx); den += ev[k]; }
  float inv = 1.f / den;

  float fagg[64];
#pragma unroll
  for (int c = 0; c < 64; c++) fagg[c] = 0.f;

#pragma unroll
  for (int k = 0; k < 9; k++) {
    float wt = ev[k] * inv;
    int ns = nsv[k];
    float wg = wt * mkv[k];
    float pn0 = xb[ns] - xc0;
    float pn1 = xb[HW_ + ns] - xc1;
    float pn2 = xb[2 * HW_ + ns] - xc2;
    float pn3 = xb[3 * HW_ + ns] - xc3;
    float gb[8];
#pragma unroll
    for (int o = 0; o < 8; o++) {
      float tg = pn0 * g1[o * 4] + pn1 * g1[o * 4 + 1] + pn2 * g1[o * 4 + 2] + pn3 * g1[o * 4 + 3];
      gb[o] = fmaxf(sG1[o] * tg + hG1[o], 0.f);
    }
    float gv[8];
#pragma unroll
    for (int j = 0; j < 8; j++) {
      float t2 = 0.f;
#pragma unroll
      for (int o = 0; o < 8; o++) t2 += gb[o] * g2[j * 8 + o];
      gv[j] = wg * fmaxf(sG2[j] * t2 + hG2[j], 0.f);
    }
    uint4 pk;
    pk.x = pack2(gv[0], gv[1]); pk.y = pack2(gv[2], gv[3]);
    pk.z = pack2(gv[4], gv[5]); pk.w = pack2(gv[6], gv[7]);
    vecA[8 + k][tid] = pk;
    float wf = wt * ibv[k];
    const float* xf = xb + 4 * HW_ + ns;
#pragma unroll
    for (int c = 0; c < 64; c++) fagg[c] += wf * xf[c * HW_];
  }
#pragma unroll
  for (int c = 0; c < 64; c += 8) {
    uint4 pk;
    pk.x = pack2(fagg[c], fagg[c + 1]);     pk.y = pack2(fagg[c + 2], fagg[c + 3]);
    pk.z = pack2(fagg[c + 4], fagg[c + 5]); pk.w = pack2(fagg[c + 6], fagg[c + 7]);
    vecA[c >> 3][tid] = pk;
  }
  __syncthreads();

  // GEMM: D[256 px][64 ch] = vecA @ w_agg^T, 16x16x32 bf16 MFMA
  int lane = tid & 63, wave = tid >> 6;
  int q = lane >> 4, r = lane & 15;

  short8 Bf[4][5];
#pragma unroll
  for (int nt = 0; nt < 4; nt++) {
    int n = nt * 16 + r;
#pragma unroll
    for (int ks = 0; ks < 5; ks++) {
      int k0 = ks * 32 + q * 8;
      uint4 pk; pk.x = pk.y = pk.z = pk.w = 0u;
      if (k0 < 136) {
        float4 f0 = *reinterpret_cast<const float4*>(w_agg + n * 136 + k0);
        float4 f1 = *reinterpret_cast<const float4*>(w_agg + n * 136 + k0 + 4);
        pk.x = pack2(f0.x, f0.y); pk.y = pack2(f0.z, f0.w);
        pk.z = pack2(f1.x, f1.y); pk.w = pack2(f1.z, f1.w);
      }
      Bf[nt][ks] = *reinterpret_cast<short8*>(&pk);
    }
  }

  floatx4 acc[4][4];
#pragma unroll
  for (int m = 0; m < 4; m++)
#pragma unroll
    for (int nt = 0; nt < 4; nt++) acc[m][nt] = (floatx4){0.f, 0.f, 0.f, 0.f};

#pragma unroll
  for (int m = 0; m < 4; m++) {
    int pix = (wave * 4 + m) * 16 + r;
    short8 Af[5];
#pragma unroll
    for (int ks = 0; ks < 5; ks++) {
      int ch = ks * 4 + q;
      if (ch < 17)
        Af[ks] = *reinterpret_cast<const short8*>(&vecA[ch][pix]);
      else
        Af[ks] = (short8){0, 0, 0, 0, 0, 0, 0, 0};
    }
#pragma unroll
    for (int nt = 0; nt < 4; nt++)
#pragma unroll
      for (int ks = 0; ks < 5; ks++)
        acc[m][nt] = __builtin_amdgcn_mfma_f32_16x16x32_bf16(Af[ks], Bf[nt][ks], acc[m][nt], 0, 0, 0);
  }

  // bf16 stores + masked abn partial stats
  float aS[4] = {0.f, 0.f, 0.f, 0.f}, aQ[4] = {0.f, 0.f, 0.f, 0.f};
  unsigned short* out_pre = (unsigned short*)((char*)ws + OUTPRE_BYTE);
  int s0 = p0 & (HW_ - 1);
#pragma unroll
  for (int m = 0; m < 4; m++) {
    int srow = s0 + (wave * 4 + m) * 16 + q * 4;
    float4 mv = *reinterpret_cast<const float4*>(mb + srow);
    float m0 = (mv.x > 0.f) ? 1.f : 0.f, m1 = (mv.y > 0.f) ? 1.f : 0.f;
    float m2 = (mv.z > 0.f) ? 1.f : 0.f, m3 = (mv.w > 0.f) ? 1.f : 0.f;
#pragma unroll
    for (int nt = 0; nt < 4; nt++) {
      int ch = nt * 16 + r;
      float o0 = acc[m][nt][0], o1 = acc[m][nt][1], o2 = acc[m][nt][2], o3 = acc[m][nt][3];
      aS[nt] += o0 * m0 + o1 * m1 + o2 * m2 + o3 * m3;
      aQ[nt] += o0 * o0 * m0 + o1 * o1 * m1 + o2 * o2 * m2 + o3 * o3 * m3;
      uint2 pk;
      pk.x = pack2(o0, o1); pk.y = pack2(o2, o3);
      *reinterpret_cast<uint2*>(out_pre + (size_t)(b * 64 + ch) * HW_ + srow) = pk;
    }
  }

  __syncthreads();  // vecA reads done; reuse for reduction
  float* rS = (float*)&vecA[0][0];  // [4][64]
  float* rQ = rS + 256;             // [4][64]
#pragma unroll
  for (int nt = 0; nt < 4; nt++) {
    float v1 = aS[nt], v2 = aQ[nt];
    v1 += __shfl_xor(v1, 16); v1 += __shfl_xor(v1, 32);
    v2 += __shfl_xor(v2, 16); v2 += __shfl_xor(v2, 32);
    if (lane < 16) { rS[wave * 64 + nt * 16 + lane] = v1; rQ[wave * 64 + nt * 16 + lane] = v2; }
  }
  __syncthreads();
  if (tid < 64) {
    atomicAdd(&ws[ATOFF + tid * 16],
              rS[tid] + rS[64 + tid] + rS[128 + tid] + rS[192 + tid]);
    atomicAdd(&ws[ATOFF + (64 + tid) * 16],
              rQ[tid] + rQ[64 + tid] + rQ[128 + tid] + rQ[192 + tid]);
  }
}

// ---- K4: abn apply + relu + center-mask zero
__global__ __launch_bounds__(256) void k_final(
    const float* __restrict__ mask, const float* __restrict__ abn_g,
    const float* __restrict__ abn_b, const float* __restrict__ ws,
    float* __restrict__ out) {
  __shared__ float sc[64], sh[64];
  if (threadIdx.x < 64) {
    int c = threadIdx.x;
    float n0 = fmaxf(ws[240], 1.f);  // slot 15 = center count
    float mean = ws[ATOFF + c * 16] / n0;
    float var = ws[ATOFF + (64 + c) * 16] / n0 - mean * mean;
    float s = abn_g[c] * rsqrtf(var + EPS);
    sc[c] = s; sh[c] = abn_b[c] - mean * s;
  }
  __syncthreads();
  const unsigned short* out_pre = (const unsigned short*)((const char*)ws + OUTPRE_BYTE);
  int i8 = (blockIdx.x * 256 + threadIdx.x) * 8;
  int c = (i8 >> 16) & 63;
  int b = i8 >> 22;
  int s = i8 & (HW_ - 1);
  uint4 v = *reinterpret_cast<const uint4*>(out_pre + i8);
  float4 ma = *reinterpret_cast<const float4*>(mask + (size_t)b * HW_ + s);
  float4 mb4 = *reinterpret_cast<const float4*>(mask + (size_t)b * HW_ + s + 4);
  float scc = sc[c], shc = sh[c];
  float4 o0, o1;
  o0.x = (ma.x > 0.f) ? fmaxf(bf2f((unsigned short)(v.x & 0xffff)) * scc + shc, 0.f) : 0.f;
  o0.y = (ma.y > 0.f) ? fmaxf(bf2f((unsigned short)(v.x >> 16)) * scc + shc, 0.f) : 0.f;
  o0.z = (ma.z > 0.f) ? fmaxf(bf2f((unsigned short)(v.y & 0xffff)) * scc + shc, 0.f) : 0.f;
  o0.w = (ma.w > 0.f) ? fmaxf(bf2f((unsigned short)(v.y >> 16)) * scc + shc, 0.f) : 0.f;
  o1.x = (mb4.x > 0.f) ? fmaxf(bf2f((unsigned short)(v.z & 0xffff)) * scc + shc, 0.f) : 0.f;
  o1.y = (mb4.y > 0.f) ? fmaxf(bf2f((unsigned short)(v.z >> 16)) * scc + shc, 0.f) : 0.f;
  o1.z = (mb4.z > 0.f) ? fmaxf(bf2f((unsigned short)(v.w & 0xffff)) * scc + shc, 0.f) : 0.f;
  o1.w = (mb4.w > 0.f) ? fmaxf(bf2f((unsigned short)(v.w >> 16)) * scc + shc, 0.f) : 0.f;
  *reinterpret_cast<float4*>(out + i8) = o0;
  *reinterpret_cast<float4*>(out + i8 + 4) = o1;
}

extern "C" void kernel_launch(void* const* d_in, const int* in_sizes, int n_in,
                              void* d_out, int out_size, void* d_ws, size_t ws_size,
                              hipStream_t stream) {
  const float* x      = (const float*)d_in[0];
  const float* mask   = (const float*)d_in[1];
  const float* w1     = (const float*)d_in[2];
  const float* bn1_g  = (const float*)d_in[3];
  const float* bn1_b  = (const float*)d_in[4];
  const float* w2     = (const float*)d_in[5];
  const float* b2     = (const float*)d_in[6];
  const float* g1     = (const float*)d_in[7];
  const float* gbn1_g = (const float*)d_in[8];
  const float* gbn1_b = (const float*)d_in[9];
  const float* g2     = (const float*)d_in[10];
  const float* gbn2_g = (const float*)d_in[11];
  const float* gbn2_b = (const float*)d_in[12];
  const float* w_agg  = (const float*)d_in[13];
  const float* abn_g  = (const float*)d_in[14];
  const float* abn_b  = (const float*)d_in[15];
  float* out = (float*)d_out;

  size_t need = (size_t)OUTPRE_BYTE + (size_t)NPIX * 64 * 2;
  if (ws_size < need) return;

  float* wsf = (float*)d_ws;
  hipMemsetAsync(d_ws, 0, OUTPRE_BYTE, stream);  // zero all atomic slots
  k_stats1<<<2048, 256, 0, stream>>>(x, mask, wsf);
  k_stats2<<<2048, 256, 0, stream>>>(x, mask, g1, gbn1_g, gbn1_b, g2, wsf);
  k_fused<<<512, 256, 0, stream>>>(x, mask, w1, bn1_g, bn1_b, w2, b2, g1,
                                   gbn1_g, gbn1_b, g2, gbn2_g, gbn2_b, w_agg, wsf);
  k_final<<<4096, 256, 0, stream>>>(mask, abn_g, abn_b, wsf, out);
}